// Round 4
// baseline (330.006 us; speedup 1.0000x reference)
//
#include <hip/hip_runtime.h>
#include <hip/hip_cooperative_groups.h>
#include <math.h>

namespace cg = cooperative_groups;

#define DD 1024
#define HD 128
#define BI 64
#define RR 36
#define BC 32
#define TT 64
#define NB 512

#define EPS_BN 1e-5f
#define EPS_L2 1e-8f
#define GAMMA_SM 10.0f
#define LOG2E 1.44269504088896f

__global__ __launch_bounds__(256, 2) void mega(
    const float* __restrict__ img, const float* __restrict__ cap,
    const float* __restrict__ Wg1, const float* __restrict__ bg1,
    const float* __restrict__ Wg2, const float* __restrict__ bg2,
    const float* __restrict__ Wb1, const float* __restrict__ bb1,
    const float* __restrict__ Wb2, const float* __restrict__ bb2,
    const int* __restrict__ lens, float* __restrict__ out,
    float* __restrict__ pc, float* __restrict__ bnpart,
    float* __restrict__ repr, float* __restrict__ capn,
    float* __restrict__ meanp, float* __restrict__ rstdp,
    float* __restrict__ hp, float* __restrict__ A, float* __restrict__ Bv,
    float* __restrict__ part4)
{
    cg::grid_group grid = cg::this_grid();
    const int bid = blockIdx.x, tid = threadIdx.x;
    __shared__ float lds[576];

    // ================= Phase 1: cap partials (256) | BN partials (256) ====
    if (bid < 256) {
        int c = bid >> 3, tg = bid & 7;
        int len = lens[c];
        const float4* p = reinterpret_cast<const float4*>(cap + (size_t)c * TT * DD) + tid;
        float4 s = {0.f, 0.f, 0.f, 0.f};
        int t0 = tg * 8;
#pragma unroll
        for (int i = 0; i < 8; i++) {
            int t = t0 + i;
            if (t < len) {
                float4 x = p[(size_t)t * 256];
                s.x += x.x; s.y += x.y; s.z += x.z; s.w += x.w;
            }
        }
        reinterpret_cast<float4*>(pc)[bid * 256 + tid] = s;
    } else {
        int g = bid - 256;   // 0..255, 9 rows each (256*9 = 2304 = BI*RR)
        const float4* p = reinterpret_cast<const float4*>(img) + (size_t)g * 9 * 256 + tid;
        float4 s = {0.f, 0.f, 0.f, 0.f}, q = {0.f, 0.f, 0.f, 0.f};
#pragma unroll
        for (int i = 0; i < 9; i++) {
            float4 x = p[(size_t)i * 256];
            s.x += x.x; s.y += x.y; s.z += x.z; s.w += x.w;
            q.x = fmaf(x.x, x.x, q.x); q.y = fmaf(x.y, x.y, q.y);
            q.z = fmaf(x.z, x.z, q.z); q.w = fmaf(x.w, x.w, q.w);
        }
        float4* bp = reinterpret_cast<float4*>(bnpart);
        bp[(g * 2 + 0) * 256 + tid] = s;
        bp[(g * 2 + 1) * 256 + tid] = q;
    }
    grid.sync();

    // ================= Phase 2: finalize repr/capn (32) | mean/rstd (32) ==
    if (bid < 32) {
        int c = bid;
        const float4* p = reinterpret_cast<const float4*>(pc) + (size_t)c * 8 * 256 + tid;
        float4 s = {0.f, 0.f, 0.f, 0.f};
#pragma unroll
        for (int g = 0; g < 8; g++) {
            float4 x = p[(size_t)g * 256];
            s.x += x.x; s.y += x.y; s.z += x.z; s.w += x.w;
        }
        float inv = 1.0f / (float)lens[c];
        float4 v = {s.x * inv, s.y * inv, s.z * inv, s.w * inv};
        reinterpret_cast<float4*>(repr)[c * 256 + tid] = v;
        float sq = fmaf(v.x, v.x, fmaf(v.y, v.y, fmaf(v.z, v.z, v.w * v.w)));
        lds[tid] = sq;
        __syncthreads();
        for (int st = 128; st > 0; st >>= 1) {
            if (tid < st) lds[tid] += lds[tid + st];
            __syncthreads();
        }
        float invn = 1.0f / (sqrtf(lds[0]) + EPS_L2);
        float4 o = {v.x * invn, v.y * invn, v.z * invn, v.w * invn};
        reinterpret_cast<float4*>(capn)[c * 256 + tid] = o;
    } else if (bid < 64) {
        int j = bid - 32;
        int dd = tid & 31, gs = tid >> 5;          // 32 d-cols x 8 g-slices
        int d = j * 32 + dd;
        float s = 0.f, q = 0.f;
        for (int g = gs; g < 256; g += 8) {
            s += bnpart[(size_t)(g * 2 + 0) * DD + d];
            q += bnpart[(size_t)(g * 2 + 1) * DD + d];
        }
        lds[gs * 32 + dd] = s;
        lds[256 + gs * 32 + dd] = q;
        __syncthreads();
        if (gs == 0) {
            float ss = 0.f, qq = 0.f;
#pragma unroll
            for (int k = 0; k < 8; k++) {
                ss += lds[k * 32 + dd];
                qq += lds[256 + k * 32 + dd];
            }
            const float invN = 1.0f / (float)(BI * RR);
            float m = ss * invN;
            float var = fmaf(-m, m, qq * invN);
            meanp[d] = m;
            rstdp[d] = rsqrtf(var + EPS_BN);
        }
    }
    grid.sync();

    // ================= Phase 3: MLP layer 1, split-K (c,kc) = 256 =========
    if (bid < 256) {
        int c = bid >> 3, kc = bid & 7;
        int h = tid & (HD - 1);
        if (tid < 128) lds[tid] = repr[c * DD + kc * 128 + tid];
        __syncthreads();
        const float* W = (tid < HD) ? Wg1 : Wb1;
        const float* Wp = W + (size_t)(kc * 128) * HD + h;
        float s0 = 0.f, s1 = 0.f, s2 = 0.f, s3 = 0.f;
#pragma unroll
        for (int d = 0; d < 128; d += 4) {
            s0 = fmaf(lds[d + 0], Wp[(size_t)(d + 0) * HD], s0);
            s1 = fmaf(lds[d + 1], Wp[(size_t)(d + 1) * HD], s1);
            s2 = fmaf(lds[d + 2], Wp[(size_t)(d + 2) * HD], s2);
            s3 = fmaf(lds[d + 3], Wp[(size_t)(d + 3) * HD], s3);
        }
        hp[((size_t)c * 8 + kc) * 256 + tid] = (s0 + s1) + (s2 + s3);
    }
    grid.sync();

    // ================= Phase 4: MLP layer 2 + BN fold (c,dg) = 256 ========
    if (bid < 256) {
        int c = bid >> 3, dg = bid & 7;
        int h = tid & (HD - 1);
        float* hid = lds;          // [0..255]
        float* ex = lds + 256;     // [256..511]
        {
            const float* hpp = hp + (size_t)c * 8 * 256 + tid;
            float s = 0.f;
#pragma unroll
            for (int k = 0; k < 8; k++) s += hpp[k * 256];
            float bias = (tid < HD) ? bg1[h] : bb1[h];
            hid[tid] = fmaxf(s + bias, 0.f);
        }
        __syncthreads();
        int gb = tid >> 7;                 // 0 = gamma, 1 = beta
        int d = dg * HD + h;
        const float* W2 = gb ? Wb2 : Wg2;
        const float* hs = hid + gb * HD;
        const float* Wp = W2 + d;
        float s0 = 0.f, s1 = 0.f, s2 = 0.f, s3 = 0.f;
#pragma unroll
        for (int hh = 0; hh < HD; hh += 4) {
            s0 = fmaf(hs[hh + 0], Wp[(size_t)(hh + 0) * DD], s0);
            s1 = fmaf(hs[hh + 1], Wp[(size_t)(hh + 1) * DD], s1);
            s2 = fmaf(hs[hh + 2], Wp[(size_t)(hh + 2) * DD], s2);
            s3 = fmaf(hs[hh + 3], Wp[(size_t)(hh + 3) * DD], s3);
        }
        float s = (s0 + s1) + (s2 + s3) + (gb ? bb2[d] : bg2[d]);
        ex[tid] = s;
        __syncthreads();
        if (tid < HD) {
            float a = ex[tid] * rstdp[d];
            float beta = ex[tid + HD];
            A[c * DD + d] = a;
            Bv[c * DD + d] = fmaf(-meanp[d], a, beta);
        }
    }
    grid.sync();

    // ================= Phase 5: fused affine+softmax+mean+dot (512) =======
    {
        int b = bid >> 3, dg = (bid >> 1) & 3, cz = bid & 1;
        int d = dg * 256 + tid;
        int lane = tid & 63, wid = tid >> 6;
        float x[RR];
        const float* ip = img + (size_t)b * RR * DD + d;
#pragma unroll
        for (int r = 0; r < RR; r++) x[r] = ip[(size_t)r * DD];
        float* sq_l = lds;        // [4][16]
        float* dt_l = lds + 64;   // [4][16]
        const float CEXP = GAMMA_SM * LOG2E;
        int c0 = cz * 16;
        for (int ci = 0; ci < 16; ci++) {
            int c = c0 + ci;
            float a  = A[c * DD + d];
            float bv = Bv[c * DD + d];
            float cn = capn[c * DD + d];
            float se = 0.f, so = 0.f;
            // |out*GAMMA| << 88 (0.02-scaled weights): no max-subtract needed
#pragma unroll
            for (int r = 0; r < RR; r++) {
                float o = fmaf(a, x[r], bv);
                float e = exp2f(o * CEXP);
                se += e;
                so = fmaf(e, o, so);
            }
            float val = so / (se * (float)RR);
            float sq = val * val;
            float dt = val * cn;
#pragma unroll
            for (int off = 32; off > 0; off >>= 1) {
                sq += __shfl_down(sq, off);
                dt += __shfl_down(dt, off);
            }
            if (lane == 0) { sq_l[wid * 16 + ci] = sq; dt_l[wid * 16 + ci] = dt; }
        }
        __syncthreads();
        if (tid < 16) {
            float sq = sq_l[0 * 16 + tid] + sq_l[1 * 16 + tid] + sq_l[2 * 16 + tid] + sq_l[3 * 16 + tid];
            float dt = dt_l[0 * 16 + tid] + dt_l[1 * 16 + tid] + dt_l[2 * 16 + tid] + dt_l[3 * 16 + tid];
            int c = c0 + tid;
            float* pp = part4 + (((size_t)b * 4 + dg) * BC + c) * 2;
            pp[0] = sq;
            pp[1] = dt;
        }
    }
    grid.sync();

    // ================= Phase 6: finalize sims (8 blocks) ===================
    if (bid < 8) {
        int e = bid * 256 + tid;   // 0..2047
        int b = e >> 5, c = e & 31;
        float sq = 0.f, dt = 0.f;
#pragma unroll
        for (int dg = 0; dg < 4; dg++) {
            const float* pp = part4 + (((size_t)b * 4 + dg) * BC + c) * 2;
            sq += pp[0];
            dt += pp[1];
        }
        out[b * BC + c] = dt / (sqrtf(sq) + EPS_L2);
    }
}

extern "C" void kernel_launch(void* const* d_in, const int* in_sizes, int n_in,
                              void* d_out, int out_size, void* d_ws, size_t ws_size,
                              hipStream_t stream) {
    const float* img = (const float*)d_in[0];   // (64,36,1024)
    const float* cap = (const float*)d_in[1];   // (32,64,1024)
    const float* Wg1 = (const float*)d_in[2];   // (1024,128)
    const float* bg1 = (const float*)d_in[3];   // (128,)
    const float* Wg2 = (const float*)d_in[4];   // (128,1024)
    const float* bg2 = (const float*)d_in[5];   // (1024,)
    const float* Wb1 = (const float*)d_in[6];
    const float* bb1 = (const float*)d_in[7];
    const float* Wb2 = (const float*)d_in[8];
    const float* bb2 = (const float*)d_in[9];
    const int* lens = (const int*)d_in[10];
    float* out = (float*)d_out;                 // (64,32)

    float* ws = (float*)d_ws;
    float* pc     = ws;              // 256*1024   = 262144
    float* bnpart = ws + 262144;     // 256*2*1024 = 524288
    float* repr   = ws + 786432;     // 32768
    float* capn   = ws + 819200;     // 32768
    float* meanp  = ws + 851968;     // 1024
    float* rstdp  = ws + 852992;     // 1024
    float* hp     = ws + 854016;     // 65536
    float* A      = ws + 919552;     // 32768
    float* Bv     = ws + 952320;     // 32768
    float* part4  = ws + 985088;     // 16384

    void* args[] = {(void*)&img, (void*)&cap,
                    (void*)&Wg1, (void*)&bg1, (void*)&Wg2, (void*)&bg2,
                    (void*)&Wb1, (void*)&bb1, (void*)&Wb2, (void*)&bb2,
                    (void*)&lens, (void*)&out,
                    (void*)&pc, (void*)&bnpart, (void*)&repr, (void*)&capn,
                    (void*)&meanp, (void*)&rstdp, (void*)&hp, (void*)&A,
                    (void*)&Bv, (void*)&part4};
    hipLaunchCooperativeKernel((const void*)mega, dim3(NB), dim3(256), args, 0, stream);
}

// Round 5
// 57.597 us; speedup vs baseline: 5.7295x; 5.7295x over previous
//
#include <hip/hip_runtime.h>
#include <math.h>

#define DD 1024
#define HD 128
#define BI 64
#define RR 36
#define BC 32
#define TT 64

#define EPS_BN 1e-5f
#define EPS_L2 1e-8f
#define GAMMA_SM 10.0f
#define LOG2E 1.44269504088896f

// ============ KA: cap partials (blocks 0..255) | BN partials (256..511) ===
__global__ __launch_bounds__(256) void kA(const float* __restrict__ cap,
                                          const int* __restrict__ lens,
                                          const float* __restrict__ img,
                                          float* __restrict__ pc,
                                          float* __restrict__ bnpart) {
    int bid = blockIdx.x, tid = threadIdx.x;
    if (bid < 256) {
        int c = bid >> 3, tg = bid & 7;
        int len = lens[c];
        const float4* p = reinterpret_cast<const float4*>(cap + (size_t)c * TT * DD) + tid;
        float4 s = {0.f, 0.f, 0.f, 0.f};
        int t0 = tg * 8;
#pragma unroll
        for (int i = 0; i < 8; i++) {
            int t = t0 + i;
            if (t < len) {
                float4 x = p[(size_t)t * 256];
                s.x += x.x; s.y += x.y; s.z += x.z; s.w += x.w;
            }
        }
        reinterpret_cast<float4*>(pc)[bid * 256 + tid] = s;
    } else {
        int g = bid - 256;   // 0..255, 9 rows each (256*9 = 2304 = BI*RR)
        const float4* p = reinterpret_cast<const float4*>(img) + (size_t)g * 9 * 256 + tid;
        float4 s = {0.f, 0.f, 0.f, 0.f}, q = {0.f, 0.f, 0.f, 0.f};
#pragma unroll
        for (int i = 0; i < 9; i++) {
            float4 x = p[(size_t)i * 256];
            s.x += x.x; s.y += x.y; s.z += x.z; s.w += x.w;
            q.x = fmaf(x.x, x.x, q.x); q.y = fmaf(x.y, x.y, q.y);
            q.z = fmaf(x.z, x.z, q.z); q.w = fmaf(x.w, x.w, q.w);
        }
        float4* bp = reinterpret_cast<float4*>(bnpart);
        bp[(g * 2 + 0) * 256 + tid] = s;
        bp[(g * 2 + 1) * 256 + tid] = q;
    }
}

// ============ KB: finalize repr/capn (0..31) | mean/rstd (32..63) =========
__global__ __launch_bounds__(256) void kB(const float* __restrict__ pc,
                                          const int* __restrict__ lens,
                                          const float* __restrict__ bnpart,
                                          float* __restrict__ repr,
                                          float* __restrict__ capn,
                                          float* __restrict__ meanp,
                                          float* __restrict__ rstdp) {
    int bid = blockIdx.x, tid = threadIdx.x;
    __shared__ float lds[512];
    if (bid < 32) {
        int c = bid;
        const float4* p = reinterpret_cast<const float4*>(pc) + (size_t)c * 8 * 256 + tid;
        float4 s = {0.f, 0.f, 0.f, 0.f};
#pragma unroll
        for (int g = 0; g < 8; g++) {
            float4 x = p[(size_t)g * 256];
            s.x += x.x; s.y += x.y; s.z += x.z; s.w += x.w;
        }
        float inv = 1.0f / (float)lens[c];
        float4 v = {s.x * inv, s.y * inv, s.z * inv, s.w * inv};
        reinterpret_cast<float4*>(repr)[c * 256 + tid] = v;
        float sq = fmaf(v.x, v.x, fmaf(v.y, v.y, fmaf(v.z, v.z, v.w * v.w)));
        lds[tid] = sq;
        __syncthreads();
        for (int st = 128; st > 0; st >>= 1) {
            if (tid < st) lds[tid] += lds[tid + st];
            __syncthreads();
        }
        float invn = 1.0f / (sqrtf(lds[0]) + EPS_L2);
        float4 o = {v.x * invn, v.y * invn, v.z * invn, v.w * invn};
        reinterpret_cast<float4*>(capn)[c * 256 + tid] = o;
    } else {
        int j = bid - 32;
        int dd = tid & 31, gs = tid >> 5;          // 32 d-cols x 8 g-slices
        int d = j * 32 + dd;
        float s = 0.f, q = 0.f;
        for (int g = gs; g < 256; g += 8) {
            s += bnpart[(size_t)(g * 2 + 0) * DD + d];
            q += bnpart[(size_t)(g * 2 + 1) * DD + d];
        }
        lds[gs * 32 + dd] = s;
        lds[256 + gs * 32 + dd] = q;
        __syncthreads();
        if (gs == 0) {
            float ss = 0.f, qq = 0.f;
#pragma unroll
            for (int k = 0; k < 8; k++) {
                ss += lds[k * 32 + dd];
                qq += lds[256 + k * 32 + dd];
            }
            const float invN = 1.0f / (float)(BI * RR);
            float m = ss * invN;
            float var = fmaf(-m, m, qq * invN);
            meanp[d] = m;
            rstdp[d] = rsqrtf(var + EPS_BN);
        }
    }
}

// ============ KC1: MLP layer 1 partials, split-K (32 c x 16 kc of 64 d) ===
__global__ __launch_bounds__(256) void kC1(const float* __restrict__ repr,
                                           const float* __restrict__ Wg1,
                                           const float* __restrict__ Wb1,
                                           float* __restrict__ hp) {
    int c = blockIdx.x, kc = blockIdx.y;
    int tid = threadIdx.x;
    int h = tid & (HD - 1);
    __shared__ float rs[64];
    if (tid < 64) rs[tid] = repr[c * DD + kc * 64 + tid];
    __syncthreads();
    const float* W = (tid < HD) ? Wg1 : Wb1;
    const float* Wp = W + (size_t)(kc * 64) * HD + h;
    float s0 = 0.f, s1 = 0.f, s2 = 0.f, s3 = 0.f;
    float s4 = 0.f, s5 = 0.f, s6 = 0.f, s7 = 0.f;
#pragma unroll
    for (int d = 0; d < 64; d += 8) {
        s0 = fmaf(rs[d + 0], Wp[(size_t)(d + 0) * HD], s0);
        s1 = fmaf(rs[d + 1], Wp[(size_t)(d + 1) * HD], s1);
        s2 = fmaf(rs[d + 2], Wp[(size_t)(d + 2) * HD], s2);
        s3 = fmaf(rs[d + 3], Wp[(size_t)(d + 3) * HD], s3);
        s4 = fmaf(rs[d + 4], Wp[(size_t)(d + 4) * HD], s4);
        s5 = fmaf(rs[d + 5], Wp[(size_t)(d + 5) * HD], s5);
        s6 = fmaf(rs[d + 6], Wp[(size_t)(d + 6) * HD], s6);
        s7 = fmaf(rs[d + 7], Wp[(size_t)(d + 7) * HD], s7);
    }
    hp[((size_t)c * 16 + kc) * 256 + tid] =
        ((s0 + s1) + (s2 + s3)) + ((s4 + s5) + (s6 + s7));
}

// ============ KC2: bias+relu, MLP layer 2, BN fold -> A, Bv (32 c x 8 dg) =
__global__ __launch_bounds__(256) void kC2(const float* __restrict__ hp,
                                           const float* __restrict__ bg1,
                                           const float* __restrict__ bb1,
                                           const float* __restrict__ Wg2,
                                           const float* __restrict__ bg2,
                                           const float* __restrict__ Wb2,
                                           const float* __restrict__ bb2,
                                           const float* __restrict__ meanp,
                                           const float* __restrict__ rstdp,
                                           float* __restrict__ A,
                                           float* __restrict__ Bv) {
    int c = blockIdx.x, dg = blockIdx.y;
    int tid = threadIdx.x;
    int h = tid & (HD - 1);
    __shared__ float hid[256];
    __shared__ float ex[256];
    {
        const float* hpp = hp + (size_t)c * 16 * 256 + tid;
        float s = 0.f;
#pragma unroll
        for (int k = 0; k < 16; k++) s += hpp[k * 256];
        float bias = (tid < HD) ? bg1[h] : bb1[h];
        hid[tid] = fmaxf(s + bias, 0.f);
    }
    __syncthreads();
    int gb = tid >> 7;                 // 0 = gamma, 1 = beta (wave-uniform)
    int d = dg * HD + h;
    const float* W2 = gb ? Wb2 : Wg2;
    const float* hs = hid + gb * HD;
    const float* Wp = W2 + d;
    float s0 = 0.f, s1 = 0.f, s2 = 0.f, s3 = 0.f;
    float s4 = 0.f, s5 = 0.f, s6 = 0.f, s7 = 0.f;
#pragma unroll
    for (int hh = 0; hh < HD; hh += 8) {
        s0 = fmaf(hs[hh + 0], Wp[(size_t)(hh + 0) * DD], s0);
        s1 = fmaf(hs[hh + 1], Wp[(size_t)(hh + 1) * DD], s1);
        s2 = fmaf(hs[hh + 2], Wp[(size_t)(hh + 2) * DD], s2);
        s3 = fmaf(hs[hh + 3], Wp[(size_t)(hh + 3) * DD], s3);
        s4 = fmaf(hs[hh + 4], Wp[(size_t)(hh + 4) * DD], s4);
        s5 = fmaf(hs[hh + 5], Wp[(size_t)(hh + 5) * DD], s5);
        s6 = fmaf(hs[hh + 6], Wp[(size_t)(hh + 6) * DD], s6);
        s7 = fmaf(hs[hh + 7], Wp[(size_t)(hh + 7) * DD], s7);
    }
    float s = ((s0 + s1) + (s2 + s3)) + ((s4 + s5) + (s6 + s7))
              + (gb ? bb2[d] : bg2[d]);
    ex[tid] = s;
    __syncthreads();
    if (tid < HD) {
        float a = ex[tid] * rstdp[d];
        float beta = ex[tid + HD];
        A[c * DD + d] = a;
        Bv[c * DD + d] = fmaf(-meanp[d], a, beta);
    }
}

// ============ KD: fused affine+softmax+mean+l2norm+dot -> sims ============
// grid (64 b, 8 cg); block covers full d=1024 (float4/thread) for 4 captions
__global__ __launch_bounds__(256, 2) void kD(const float* __restrict__ img,
                                             const float* __restrict__ A,
                                             const float* __restrict__ Bv,
                                             const float* __restrict__ capn,
                                             float* __restrict__ sims) {
    int b = blockIdx.x, cg = blockIdx.y;
    int tid = threadIdx.x;
    int lane = tid & 63, wid = tid >> 6;
    const float4* ip = reinterpret_cast<const float4*>(img + (size_t)b * RR * DD) + tid;
    float4 x[RR];
#pragma unroll
    for (int r = 0; r < RR; r++) x[r] = ip[(size_t)r * 256];
    __shared__ float sq_l[4][4], dt_l[4][4];
    const float CEXP = GAMMA_SM * LOG2E;
    for (int ci = 0; ci < 4; ci++) {
        int c = cg * 4 + ci;
        float4 a  = reinterpret_cast<const float4*>(A)[c * 256 + tid];
        float4 bv = reinterpret_cast<const float4*>(Bv)[c * 256 + tid];
        float4 cn = reinterpret_cast<const float4*>(capn)[c * 256 + tid];
        float4 se = {0.f, 0.f, 0.f, 0.f}, so = {0.f, 0.f, 0.f, 0.f};
        // |out*GAMMA| << 88 (0.02-scaled weights): no max-subtract needed
#pragma unroll
        for (int r = 0; r < RR; r++) {
            float4 o;
            o.x = fmaf(a.x, x[r].x, bv.x);
            o.y = fmaf(a.y, x[r].y, bv.y);
            o.z = fmaf(a.z, x[r].z, bv.z);
            o.w = fmaf(a.w, x[r].w, bv.w);
            float ex_ = exp2f(o.x * CEXP);
            float ey = exp2f(o.y * CEXP);
            float ez = exp2f(o.z * CEXP);
            float ew = exp2f(o.w * CEXP);
            se.x += ex_; se.y += ey; se.z += ez; se.w += ew;
            so.x = fmaf(ex_, o.x, so.x);
            so.y = fmaf(ey, o.y, so.y);
            so.z = fmaf(ez, o.z, so.z);
            so.w = fmaf(ew, o.w, so.w);
        }
        const float invR = 1.0f / (float)RR;
        float4 val = {so.x / se.x * invR, so.y / se.y * invR,
                      so.z / se.z * invR, so.w / se.w * invR};
        float sq  = fmaf(val.x, val.x, fmaf(val.y, val.y, fmaf(val.z, val.z, val.w * val.w)));
        float dt  = fmaf(val.x, cn.x, fmaf(val.y, cn.y, fmaf(val.z, cn.z, val.w * cn.w)));
#pragma unroll
        for (int off = 32; off > 0; off >>= 1) {
            sq += __shfl_down(sq, off);
            dt += __shfl_down(dt, off);
        }
        if (lane == 0) { sq_l[wid][ci] = sq; dt_l[wid][ci] = dt; }
    }
    __syncthreads();
    if (tid < 4) {
        float sq = sq_l[0][tid] + sq_l[1][tid] + sq_l[2][tid] + sq_l[3][tid];
        float dt = dt_l[0][tid] + dt_l[1][tid] + dt_l[2][tid] + dt_l[3][tid];
        sims[b * BC + cg * 4 + tid] = dt / (sqrtf(sq) + EPS_L2);
    }
}

extern "C" void kernel_launch(void* const* d_in, const int* in_sizes, int n_in,
                              void* d_out, int out_size, void* d_ws, size_t ws_size,
                              hipStream_t stream) {
    const float* img = (const float*)d_in[0];   // (64,36,1024)
    const float* cap = (const float*)d_in[1];   // (32,64,1024)
    const float* Wg1 = (const float*)d_in[2];   // (1024,128)
    const float* bg1 = (const float*)d_in[3];   // (128,)
    const float* Wg2 = (const float*)d_in[4];   // (128,1024)
    const float* bg2 = (const float*)d_in[5];   // (1024,)
    const float* Wb1 = (const float*)d_in[6];
    const float* bb1 = (const float*)d_in[7];
    const float* Wb2 = (const float*)d_in[8];
    const float* bb2 = (const float*)d_in[9];
    const int* lens = (const int*)d_in[10];
    float* out = (float*)d_out;                 // (64,32)

    float* ws = (float*)d_ws;
    float* pc     = ws;              // 256*1024   = 262144
    float* bnpart = ws + 262144;     // 256*2*1024 = 524288
    float* repr   = ws + 786432;     // 32768
    float* capn   = ws + 819200;     // 32768
    float* meanp  = ws + 851968;     // 1024
    float* rstdp  = ws + 852992;     // 1024
    float* hp     = ws + 854016;     // 32*16*256 = 131072
    float* A      = ws + 985088;     // 32768
    float* Bv     = ws + 1017856;    // 32768

    kA<<<512, 256, 0, stream>>>(cap, lens, img, pc, bnpart);
    kB<<<64, 256, 0, stream>>>(pc, lens, bnpart, repr, capn, meanp, rstdp);
    kC1<<<dim3(BC, 16), 256, 0, stream>>>(repr, Wg1, Wb1, hp);
    kC2<<<dim3(BC, 8), 256, 0, stream>>>(hp, bg1, bb1, Wg2, bg2, Wb2, bb2,
                                         meanp, rstdp, A, Bv);
    kD<<<dim3(BI, 8), 256, 0, stream>>>(img, A, Bv, capn, out);
}